// Round 8
// baseline (282.953 us; speedup 1.0000x reference)
//
#include <hip/hip_runtime.h>

// RT-DETRv2 multiscale deformable attention, MI355X/gfx950.
// B=16, Q=300, S=8400 (80x80+40x40+20x20), D=256, H=8, HD=32, L=3, P=4, LP=12.
// Inputs fp32, output fp32 (verified; absmax 1.2e-3 vs thr 2.7e-3).
//
//   K0 prep:      pre-swizzle weights fp32->bf16 into B-fragment order
//   K1 gemm128 (R15): same 2-barrier 128x128 skeleton, but 8 waves x 512 thr,
//                 acc[2][4] = 32 AGPR/wave. THEORY: VGPR_Count=84 EXCLUDES the
//                 64 AGPRs; unified file -> 148 regs -> 2 waves/SIMD band
//                 (matches measured 27% occ all rounds). Halving acc + LB(512,4)
//                 targets <=128 total -> 4 waves/SIMD -> convoy overlap doubles.
//   K2 proj_gemm: grid 300, 16 q/block, direct-B, barrier-free GEMM (R13)
//   K34 sample_out: fused sampling + output GEMM (R14)
//
// Measured laws so far:
//  - acc 32 f32x4 (276 regs) -> 1 wave/SIMD (83->121/137 us). acc 16 f32x4
//    (84+64=148 regs) -> 2 waves/SIMD (occ 27%, 83 us). R15 tests the next
//    band: acc 8 f32x4, total <=128 -> 4 waves/SIMD.
//  - K1 schedule variants at FIXED 2-wave/SIMD occupancy all ~82-90 us
//    (R4-R9); L2-direct 1-deep (R10) 112; B-in-LDS 128KB (R12) 177.
//    TLP, not intra-wave schedule, is the binding resource.
//  - Inputs+ws are L3-resident across iterations (R10 FETCH 68.8MB < A size).
//  - cvtpk halves VALUBusy, zero time change -> VALU never on critical path.
//  - R13 K2/K4 de-convoy: -9.5 us. R14 K3+K4 fusion: +-0. Small-kernel
//    surface exhausted; rest-minus-kernels ~160 us = harness resets (fixed).

typedef __attribute__((ext_vector_type(8))) short short8;   // MFMA A/B frag (8 bf16)
typedef __attribute__((ext_vector_type(4))) short short4v;  // 4 bf16 (8B)
typedef __attribute__((ext_vector_type(4))) float f32x4;    // MFMA accumulator

__device__ __forceinline__ unsigned short f2bf(float f) {   // fp32 -> bf16 RTNE
    union { float f; unsigned int i; } v; v.f = f;
    unsigned int r = v.i + 0x7FFFu + ((v.i >> 16) & 1u);
    return (unsigned short)(r >> 16);
}
__device__ __forceinline__ float bf2f(unsigned short u) {
    union { unsigned int i; float f; } v;
    v.i = ((unsigned int)u) << 16;
    return v.f;
}
__device__ __forceinline__ short8 cvt8(const float* p) {
    f32x4 x = *(const f32x4*)p;
    f32x4 y = *(const f32x4*)(p + 4);
    short8 r;
#pragma unroll
    for (int q = 0; q < 4; ++q) {
        r[q]     = (short)f2bf(x[q]);
        r[q + 4] = (short)f2bf(y[q]);
    }
    return r;
}
__device__ __forceinline__ void barrier_lgkm() {
    asm volatile("s_waitcnt lgkmcnt(0)\n\ts_barrier" ::: "memory");
}

// ---- K0: pre-swizzle weights into B-fragment order (bf16) ------------------
// Slot s = kcb*1024 + tile*64 + fragLane holds
// W[n = tile*16 + (fl&15)][kcb*32 + (fl>>4)*8 .. +8).  Proj W: 18 n-tiles
// (288 rows = w_off ++ w_attn), 1152 slots/kcb.
__global__ __launch_bounds__(256) void prep_kernel(
    const float* __restrict__ wv, const float* __restrict__ wo,
    const float* __restrict__ w_off, const float* __restrict__ w_attn,
    short8* __restrict__ wv_s, short8* __restrict__ wo_s, short8* __restrict__ wp_s)
{
    const int blk = blockIdx.x, tid = threadIdx.x;
    if (blk < 64) {
        const float* W = (blk < 32) ? wv : wo;
        short8* out    = (blk < 32) ? wv_s : wo_s;
        int s   = ((blk & 31) << 8) + tid;
        int kcb = s >> 10, sl = s & 1023;
        int n = ((sl >> 6) << 4) + (sl & 15);
        int k = (kcb << 5) + (((sl >> 4) & 3) << 3);
        out[s] = cvt8(W + n * 256 + k);
    } else {
        int s   = ((blk - 64) << 8) + tid;
        int kcb = s / 1152, sl = s - kcb * 1152;
        int n = ((sl >> 6) << 4) + (sl & 15);
        int k = (kcb << 5) + (((sl >> 4) & 3) << 3);
        const float* p = (n < 192) ? (w_off + (size_t)n * 256 + k)
                                   : (w_attn + (size_t)(n - 192) * 256 + k);
        wp_s[s] = cvt8(p);
    }
}

// ---- K1 (R15): C[M x 256] = A @ W^T + bias, 128x128 tile, 8 waves ----------
// Grid (M/128)*2 x 512 threads. blockIdx>>1 = row block, &1 = col half.
// Wave w: mq = w>>1 (32-row band), nq = w&1 (64-col half); acc[2][4] = 32 AGPR.
// Staging: 1 A slot + 1 B slot per thread (512 each). Per wave per kcb:
// 6 ds_read_b128 + 8 MFMA. __launch_bounds__(512,4) caps regs at 128 ->
// target 4 waves/SIMD (2 blocks/CU co-resident).
__global__ __launch_bounds__(512, 4) void gemm128(
    const float* __restrict__ A,
    const short8* __restrict__ Wswz,
    const float* __restrict__ bias,
    unsigned short* __restrict__ C)
{
    __shared__ short8 lb[1024];   // 16 KiB: A slots [0,512), B slots [512,1024)
    const int tid  = threadIdx.x;
    const int wave = tid >> 6;                  // 0..7
    const int lane = tid & 63;
    const int row0 = (blockIdx.x >> 1) * 128;
    const int colt = blockIdx.x & 1;            // which 128-col half
    const int mq   = wave >> 1;                 // 32-row band (0..3)
    const int nq   = wave & 1;                  // 64-col half (0..1)

    f32x4 acc[2][4];
#pragma unroll
    for (int i = 0; i < 2; ++i)
#pragma unroll
        for (int j = 0; j < 4; ++j) acc[i][j] = (f32x4){0.f, 0.f, 0.f, 0.f};

    // staging indices: one A slot (= tid) per thread
    const int am0 = row0 + ((tid >> 6) << 4) + (tid & 15);
    const int ak0 = ((tid >> 4) & 3) << 3;

    for (int kcb = 0; kcb < 8; ++kcb) {
        const int kc = kcb << 5;
        barrier_lgkm();
        // A tile: 512 slots in fragment order (1 per thread)
        lb[tid] = cvt8(A + (size_t)am0 * 256 + kc + ak0);
        // B tile: contiguous 512-slot copy of this col-half's 8 n-tiles
        lb[512 + tid] = Wswz[(kcb << 10) + (colt << 9) + tid];
        barrier_lgkm();

        short8 af[2], bf[4];
#pragma unroll
        for (int i = 0; i < 2; ++i) af[i] = lb[((mq << 1) + i) * 64 + lane];
#pragma unroll
        for (int j = 0; j < 4; ++j) bf[j] = lb[512 + ((nq << 2) + j) * 64 + lane];
#pragma unroll
        for (int i = 0; i < 2; ++i)
#pragma unroll
            for (int j = 0; j < 4; ++j)
                acc[i][j] = __builtin_amdgcn_mfma_f32_16x16x32_bf16(af[i], bf[j], acc[i][j], 0, 0, 0);
    }

    // epilogue: D row = row0 + (mq*2+i)*16 + (lane>>4)*4 + r,
    //           col = colt*128 + (nq*4+j)*16 + (lane&15)
    const int ncol = lane & 15;
    const int rsub = (lane >> 4) << 2;
#pragma unroll
    for (int i = 0; i < 2; ++i) {
        const int rb = row0 + ((mq << 1) + i) * 16 + rsub;
#pragma unroll
        for (int j = 0; j < 4; ++j) {
            const int n = (colt << 7) + ((nq << 2) + j) * 16 + ncol;
            const float bv = bias[n];
#pragma unroll
            for (int r = 0; r < 4; ++r)
                C[(size_t)(rb + r) * 256 + n] = f2bf(acc[i][j][r] + bv);
        }
    }
}

// ---- K2: proj logits, barrier-free direct-B + fused softmax/loc ------------
// Grid 300 x 256: 16 queries/block. Wave w owns n-tiles [ts, ts+tc):
// {0-4},{5-9},{10-13},{14-17}. Per kcb (fully unrolled): 1 cvt8 A + tc
// direct B loads (L2/L3-resident wp_s) + tc MFMA. No __syncthreads until
// the logits-LDS exchange. LDS = 16 x LGS floats (19 KB).
#define LGS 296   // padded LDS row stride (floats)
__global__ __launch_bounds__(256) void proj_gemm(
    const float* __restrict__ hidden,
    const short8* __restrict__ Wswz,
    const float* __restrict__ b_off, const float* __restrict__ b_attn,
    const float* __restrict__ refp,
    float* __restrict__ attnw, float* __restrict__ locw)
{
    __shared__ float lg[16 * LGS];

    const int tid  = threadIdx.x;
    const int wave = tid >> 6;
    const int lane = tid & 63;
    const int rq0  = blockIdx.x * 16;

    const int ts = (wave < 2) ? wave * 5 : 10 + ((wave - 2) << 2);
    const int tc = (wave < 2) ? 5 : 4;

    f32x4 acc[5];
#pragma unroll
    for (int t = 0; t < 5; ++t) acc[t] = (f32x4){0.f, 0.f, 0.f, 0.f};

    const int am = rq0 + (lane & 15);
    const int kq = (lane >> 4) << 3;

#pragma unroll
    for (int kcb = 0; kcb < 8; ++kcb) {
        short8 a = cvt8(hidden + (size_t)am * 256 + (kcb << 5) + kq);
        const short8* bb = Wswz + kcb * 1152 + (ts << 6) + lane;
#pragma unroll
        for (int t = 0; t < 5; ++t)
            if (t < tc)
                acc[t] = __builtin_amdgcn_mfma_f32_16x16x32_bf16(a, bb[t << 6], acc[t], 0, 0, 0);
    }

    // logits -> LDS (rows 0..15 of this block)
    const int ncol = lane & 15;
    const int rb   = (lane >> 4) << 2;
#pragma unroll
    for (int t = 0; t < 5; ++t) {
        if (t < tc) {
            int n = ((ts + t) << 4) + ncol;
            float bv = (n < 192) ? b_off[n] : b_attn[n - 192];
#pragma unroll
            for (int r = 0; r < 4; ++r)
                lg[(rb + r) * LGS + n] = acc[t][r] + bv;
        }
    }
    __syncthreads();

    if (tid < 128) {   // softmax: 16 rows x 8 heads, one per thread
        int r = tid >> 3, h = tid & 7;
        const float* lrow = lg + r * LGS + 192 + h * 12;
        float m = -1e30f;
#pragma unroll
        for (int p = 0; p < 12; ++p) m = fmaxf(m, lrow[p]);
        float e[12], sum = 0.f;
#pragma unroll
        for (int p = 0; p < 12; ++p) { e[p] = __expf(lrow[p] - m); sum += e[p]; }
        float inv = 1.f / sum;
        float* ao = attnw + (size_t)(rq0 + r) * 96 + h * 12;
#pragma unroll
        for (int p = 0; p < 12; ++p) ao[p] = e[p] * inv;
    }
    if (tid < 192) {   // loc = ref_xy + logit*0.125*ref_wh
        int xy = tid & 1;
#pragma unroll
        for (int r = 0; r < 16; ++r) {
            int rq = rq0 + r;
            float rc  = refp[(size_t)rq * 4 + xy];
            float rwh = refp[(size_t)rq * 4 + 2 + xy];
            locw[(size_t)rq * 192 + tid] = rc + lg[r * LGS + tid] * 0.125f * rwh;
        }
    }
}

// ---- K34: fused sampling + output GEMM -------------------------------------
// Grid 300 x 512 (8 waves): 16 rq/block.
// Phase A: corner tables for 16x96 points; wave w gathers rq {2w, 2w+1}
//   (h = lane>>3, cq = (lane&7)*4; 48 ushort4 8B gathers per rq) -> LDS
//   sampled[16][264] bf16 (stride 264 = +8 pad: A-frag ds_reads land 2-way
//   bank-aliased across 16 rows = free).
// Phase B: out = sampled @ w_out^T + b_out. Wave w owns n-tiles {2w, 2w+1};
//   per kcb: 1 ds_read_b128 A-frag + 2 direct B loads + 2 MFMA; acc[2].
#define SSTR 264
__global__ __launch_bounds__(512) void sample_out_kernel(
    const unsigned short* __restrict__ value,   // bf16 [b][s][h][32]
    const float* __restrict__ attnw, const float* __restrict__ locw,
    const short8* __restrict__ Wswz,            // wo_swz
    const float* __restrict__ bias,             // b_out
    float* __restrict__ Cv)                     // d_out fp32 [4800][256]
{
    const int rq0 = blockIdx.x << 4;
    const int tid = threadIdx.x;

    __shared__ int4           soff[16][96];
    __shared__ float4         swt[16][96];
    __shared__ unsigned short slds[16 * SSTR];  // sampled bf16, padded stride

    // setup: 1536 items (16 rq x 96 (h,lp)) across 512 threads
    for (int it = tid; it < 1536; it += 512) {
        int rsub = it / 96;
        int idx  = it - rsub * 96;
        int rq   = rq0 + rsub;
        int b    = rq / 300;
        int h  = idx / 12, lp = idx - h * 12;
        int l  = lp >> 2;
        int Wl = (l == 0) ? 80 : (l == 1) ? 40 : 20;        // H == W per level
        int s0 = (l == 0) ? 0  : (l == 1) ? 6400 : 8000;
        float lx = locw[(size_t)rq * 192 + h * 24 + lp * 2];
        float ly = locw[(size_t)rq * 192 + h * 24 + lp * 2 + 1];
        float aw = attnw[(size_t)rq * 96 + h * 12 + lp];
        float gx = lx * (float)Wl - 0.5f;
        float gy = ly * (float)Wl - 0.5f;
        float x0f = floorf(gx), y0f = floorf(gy);
        int   x0 = (int)x0f,   y0 = (int)y0f;
        float wx1 = gx - x0f, wx0 = 1.f - wx1;
        float wy1 = gy - y0f, wy0 = 1.f - wy1;
        int4 of; float4 wt;
#pragma unroll
        for (int j = 0; j < 4; ++j) {
            int x = x0 + (j & 1), y = y0 + (j >> 1);
            bool ok = (x >= 0) & (x < Wl) & (y >= 0) & (y < Wl);
            int idx2 = ok ? (((b * 8400 + s0 + y * Wl + x) * 8 + h) * 32) : 0;
            float w = ok ? aw * ((j & 1) ? wx1 : wx0) * ((j >> 1) ? wy1 : wy0) : 0.f;
            ((int*)&of)[j] = idx2;
            ((float*)&wt)[j] = w;
        }
        soff[rsub][idx] = of;
        swt[rsub][idx]  = wt;
    }
    __syncthreads();

    const int wave = tid >> 6;
    const int lane = tid & 63;
    {   // gather: wave w handles rq pair {2w, 2w+1}
        const int h  = lane >> 3;
        const int cq = (lane & 7) << 2;
        const int base = h * 12;
#pragma unroll
        for (int sub = 0; sub < 2; ++sub) {
            const int rsub = (wave << 1) + sub;
            float acc0 = 0.f, acc1 = 0.f, acc2 = 0.f, acc3 = 0.f;
#pragma unroll
            for (int lp = 0; lp < 12; ++lp) {
                int4   of = soff[rsub][base + lp];
                float4 wt = swt[rsub][base + lp];
#pragma unroll
                for (int j = 0; j < 4; ++j) {
                    int   o = ((const int*)&of)[j];
                    float w = ((const float*)&wt)[j];
                    uint2 u = *(const uint2*)(value + o + cq);   // 4 bf16 ch
                    union { unsigned int i; float f; } c0, c1, c2, c3;
                    c0.i = u.x << 16; c1.i = u.x & 0xFFFF0000u;
                    c2.i = u.y << 16; c3.i = u.y & 0xFFFF0000u;
                    acc0 += w * c0.f; acc1 += w * c1.f;
                    acc2 += w * c2.f; acc3 += w * c3.f;
                }
            }
            short4v s;
            s[0] = (short)f2bf(acc0);
            s[1] = (short)f2bf(acc1);
            s[2] = (short)f2bf(acc2);
            s[3] = (short)f2bf(acc3);
            *(short4v*)(slds + rsub * SSTR + h * 32 + cq) = s;
        }
    }
    __syncthreads();

    // Phase B: 16x256 GEMM. A-frag row = lane&15, k-chunk = (lane>>4)*8.
    f32x4 acc[2];
    acc[0] = (f32x4){0.f, 0.f, 0.f, 0.f};
    acc[1] = (f32x4){0.f, 0.f, 0.f, 0.f};

    const int am = lane & 15;
    const int kq = (lane >> 4) << 3;

#pragma unroll
    for (int kcb = 0; kcb < 8; ++kcb) {
        short8 a = *(const short8*)(slds + am * SSTR + (kcb << 5) + kq);
        const short8* bb = Wswz + (kcb << 10) + (wave << 7) + lane;
        acc[0] = __builtin_amdgcn_mfma_f32_16x16x32_bf16(a, bb[0],  acc[0], 0, 0, 0);
        acc[1] = __builtin_amdgcn_mfma_f32_16x16x32_bf16(a, bb[64], acc[1], 0, 0, 0);
    }

    const int ncol = lane & 15;
    const int rb   = rq0 + ((lane >> 4) << 2);
#pragma unroll
    for (int t = 0; t < 2; ++t) {
        int n = (wave << 5) + (t << 4) + ncol;
        float bv = bias[n];
#pragma unroll
        for (int r = 0; r < 4; ++r)
            Cv[(size_t)(rb + r) * 256 + n] = acc[t][r] + bv;
    }
}

extern "C" void kernel_launch(void* const* d_in, const int* in_sizes, int n_in,
                              void* d_out, int out_size, void* d_ws, size_t ws_size,
                              hipStream_t stream)
{
    const float* hidden  = (const float*)d_in[0];
    const float* enc     = (const float*)d_in[1];
    const float* refp    = (const float*)d_in[2];
    const float* w_value = (const float*)d_in[3];
    const float* b_value = (const float*)d_in[4];
    const float* w_off   = (const float*)d_in[5];
    const float* b_off   = (const float*)d_in[6];
    const float* w_attn  = (const float*)d_in[7];
    const float* b_attn  = (const float*)d_in[8];
    const float* w_out   = (const float*)d_in[9];
    const float* b_out   = (const float*)d_in[10];

    // ws layout: value 68,812,800 | (sampled slot unused since R14) |
    // attnw 1,843,200 | locw 3,686,400 | wv_swz | wo_swz | wp_swz
    char* ws = (char*)d_ws;
    unsigned short* value   = (unsigned short*)ws;
    float*          attnw   = (float*)(ws + 71270400);
    float*          locw    = (float*)(ws + 73113600);
    short8*         wv_swz  = (short8*)(ws + 76800000);
    short8*         wo_swz  = (short8*)(ws + 76931072);
    short8*         wp_swz  = (short8*)(ws + 77062144);

    prep_kernel<<<100, 256, 0, stream>>>(w_value, w_out, w_off, w_attn,        // K0
                                         wv_swz, wo_swz, wp_swz);
    gemm128<<<2100, 512, 0, stream>>>(enc, wv_swz, b_value, value);            // K1
    proj_gemm<<<300, 256, 0, stream>>>(hidden, wp_swz, b_off, b_attn,          // K2
                                       refp, attnw, locw);
    sample_out_kernel<<<300, 512, 0, stream>>>(value, attnw, locw,             // K34
                                               wo_swz, b_out, (float*)d_out);
}